// Round 6
// baseline (827.265 us; speedup 1.0000x reference)
//
#include <hip/hip_runtime.h>

// ---------------------------------------------------------------------------
// VectorQuantizer, np-fp32-faithful argmin. Round 11 = round 10 + reg-scan:
//   THEORY: LDS pipe ~65% of gemm wall; scorebuf round-trip (write+read+
//   3-way bank conflicts on stride-67 writes; SQ_LDS_BANK_CONFLICT == 2^24
//   every round) ~= 185k cyc/CU of pure layout-transposition waste.
//   FIX (T12 swapped-operand): mfma(code_frag, row_frag) -> C/D has codes on
//   the reg axis (quad*4+r) and z-rows on the lane axis (lcol). Each lane
//   holds 16 codes x 4 rows in registers -> top-4 insertion fully in-reg
//   (strict <, ascending-id traversal == old tie semantics), one butterfly
//   merge across quad-lanes ((key,id) lexicographic -> deterministic) at the
//   end. Per-(row,by,wn) top-4 -> same 64 candidates/row + margin rescue.
//   Scorebuf + its 4 barriers/ct + all its LDS traffic deleted.
//   - round-10 pipeline kept: triple-buffer 24KB, STAGE-after-barrier,
//     counted vmcnt(3) (never 0 in loop), BK=32, M-tile 256, grid 1024
//   - swizzle: slot s of row r holds chunk s ^ ((r>>1)&3) (2-way, free)
// Scratch inside d_out quantized region (overwritten by writeout_k):
//   [0) zb 32MB][32M) eb 8MB][40M) b32 32KB][+32K) a32 128KB]
//   [+128K) candk 8MB][+8M) candi 8MB]   (ends ~58.9MB < 64MB)
// d_ws: 8 bytes (loss accumulator).
// ---------------------------------------------------------------------------

#define N_ROWS 32768
#define K_CODES 8192
#define DIM 512

typedef __attribute__((ext_vector_type(8))) short short8;
typedef __attribute__((ext_vector_type(4))) float f32x4;

#define MARGIN 5e-4f

__device__ __forceinline__ unsigned short f2bf(float f) {
  unsigned int u = __float_as_uint(f);
  u = u + 0x7fffu + ((u >> 16) & 1u);   // round-to-nearest-even
  return (unsigned short)(u >> 16);
}

__device__ __forceinline__ double shfl_xor_dbl(double v, int m) {
  union { double d; int i[2]; } u;
  u.d = v;
  u.i[0] = __shfl_xor(u.i[0], m, 64);
  u.i[1] = __shfl_xor(u.i[1], m, 64);
  return u.d;
}

// opaque: block fp contraction across this value (keep separate RN32 steps)
__device__ __forceinline__ float opaque_f(float x) {
  asm volatile("" : "+v"(x));
  return x;
}

// ------- 1) fused fp32 -> bf16 + row squared-norm (one wave per row) -------
__global__ __launch_bounds__(256) void cvtnorm_k(const float* __restrict__ in,
                                                 unsigned short* __restrict__ outb,
                                                 float* __restrict__ outn) {
  const int r = blockIdx.x * 4 + (threadIdx.x >> 6);
  const int lane = threadIdx.x & 63;
  const float* xr = in + (size_t)r * DIM + lane * 8;
  const float4 a = *(const float4*)xr;
  const float4 b = *(const float4*)(xr + 4);
  uint4 o;
  o.x = (unsigned)f2bf(a.x) | ((unsigned)f2bf(a.y) << 16);
  o.y = (unsigned)f2bf(a.z) | ((unsigned)f2bf(a.w) << 16);
  o.z = (unsigned)f2bf(b.x) | ((unsigned)f2bf(b.y) << 16);
  o.w = (unsigned)f2bf(b.z) | ((unsigned)f2bf(b.w) << 16);
  *(uint4*)(outb + (size_t)r * DIM + lane * 8) = o;
  double s = (double)a.x * a.x + (double)a.y * a.y + (double)a.z * a.z + (double)a.w * a.w
           + (double)b.x * b.x + (double)b.y * b.y + (double)b.z * b.z + (double)b.w * b.w;
#pragma unroll
  for (int m = 1; m < 64; m <<= 1) s += shfl_xor_dbl(s, m);
  if (lane == 0) outn[r] = (float)s;
}

// ---------------- 2) bf16 GEMM + fused in-register top-4 -------------------
// grid 1024: bx=blk>>3 -> 256 z-rows; by=blk&7 -> 1024-code chunk (ct<8).
// Block 512 = 8 waves 4x2 (wm rows x wn code-half); wave tile 64 rows x 64
// codes = 4x4 MFMA 16x16x32 with SWAPPED operands: acc[i][j] i=code-block,
// j=row-block; lane holds codes (quad*4+r, i) for rows (j*16+lcol).
// Triple-buffered staging (24KB each): 0 / 24576 / 49152; e2sAll at 73728.
// LDS total 77824 -> 2 blocks/CU. No scorebuf.
// Swizzle: row r (64B) slot s holds source chunk s ^ ((r>>1)&3).

#define DECL_TOPK(J) \
  float tk##J##0 = 3.4e38f, tk##J##1 = 3.4e38f, tk##J##2 = 3.4e38f, tk##J##3 = 3.4e38f; \
  int ti##J##0 = 0, ti##J##1 = 0, ti##J##2 = 0, ti##J##3 = 0;

// hot-path insert: strict key-<; ascending-id traversal keeps earliest id
#define INS(J, sv, idv) do { \
    if ((sv) < tk##J##3) { \
      if ((sv) < tk##J##2) { tk##J##3 = tk##J##2; ti##J##3 = ti##J##2; \
        if ((sv) < tk##J##1) { tk##J##2 = tk##J##1; ti##J##2 = ti##J##1; \
          if ((sv) < tk##J##0) { tk##J##1 = tk##J##0; ti##J##1 = ti##J##0; tk##J##0 = (sv); ti##J##0 = (idv); } \
          else { tk##J##1 = (sv); ti##J##1 = (idv); } \
        } else { tk##J##2 = (sv); ti##J##2 = (idv); } \
      } else { tk##J##3 = (sv); ti##J##3 = (idv); } \
    } \
  } while (0)

// merge insert: full lexicographic (key,id) -> symmetric deterministic merge
#define LTL(sv, idv, K, I) ((sv) < (K) || ((sv) == (K) && (idv) < (I)))
#define INSM(J, sv, idv) do { \
    if (LTL(sv, idv, tk##J##3, ti##J##3)) { \
      if (LTL(sv, idv, tk##J##2, ti##J##2)) { tk##J##3 = tk##J##2; ti##J##3 = ti##J##2; \
        if (LTL(sv, idv, tk##J##1, ti##J##1)) { tk##J##2 = tk##J##1; ti##J##2 = ti##J##1; \
          if (LTL(sv, idv, tk##J##0, ti##J##0)) { tk##J##1 = tk##J##0; ti##J##1 = ti##J##0; tk##J##0 = (sv); ti##J##0 = (idv); } \
          else { tk##J##1 = (sv); ti##J##1 = (idv); } \
        } else { tk##J##2 = (sv); ti##J##2 = (idv); } \
      } else { tk##J##3 = (sv); ti##J##3 = (idv); } \
    } \
  } while (0)

#define SCAN_J(J) do { \
    float s0_ = fmaf(acc[i][J][0], -2.0f, e0), s1_ = fmaf(acc[i][J][1], -2.0f, e1); \
    float s2_ = fmaf(acc[i][J][2], -2.0f, e2v), s3_ = fmaf(acc[i][J][3], -2.0f, e3); \
    const float mn_ = fminf(fminf(s0_, s1_), fminf(s2_, s3_)); \
    if (mn_ < tk##J##3) { \
      INS(J, s0_, id0); INS(J, s1_, id0 + 1); INS(J, s2_, id0 + 2); INS(J, s3_, id0 + 3); \
    } \
  } while (0)

#define MERGE_STEP(J, M) do { \
    float ok0 = __shfl_xor(tk##J##0, M, 64), ok1 = __shfl_xor(tk##J##1, M, 64); \
    float ok2 = __shfl_xor(tk##J##2, M, 64), ok3 = __shfl_xor(tk##J##3, M, 64); \
    int oi0 = __shfl_xor(ti##J##0, M, 64), oi1 = __shfl_xor(ti##J##1, M, 64); \
    int oi2 = __shfl_xor(ti##J##2, M, 64), oi3 = __shfl_xor(ti##J##3, M, 64); \
    INSM(J, ok0, oi0); INSM(J, ok1, oi1); INSM(J, ok2, oi2); INSM(J, ok3, oi3); \
  } while (0)

__global__ __launch_bounds__(512, 4) void gemm_topk(
    const unsigned short* __restrict__ A,   // z bf16 [32768][512]
    const unsigned short* __restrict__ B,   // e bf16 [8192][512]
    const float* __restrict__ en2,          // [8192] = b32
    float* __restrict__ candk,              // [32768][64]
    int* __restrict__ candi)                // [32768][64]
{
  __shared__ char lds[77824];
  float* e2sAll = (float*)(lds + 73728);         // [1024]

  const int tid = threadIdx.x;
  const int lane = tid & 63, wave = tid >> 6;    // wave 0..7
  const int wm = wave >> 1, wn = wave & 1;       // 4x2 wave grid
  const int quad = lane >> 4, lcol = lane & 15;
  const int bx = blockIdx.x >> 3, by = blockIdx.x & 7;
  const int row0 = bx * 256;
  const int cstart = by * 1024;                  // FULL coverage: 8 x 1024

  // preload all 1024 e-norms for this chunk (keeps VMEM out of vmcnt count)
  e2sAll[tid] = en2[cstart + tid];
  e2sAll[tid + 512] = en2[cstart + 512 + tid];

  DECL_TOPK(0) DECL_TOPK(1) DECL_TOPK(2) DECL_TOPK(3)

  // staging: lane l covers (row = base + (l>>2), lds-slot = l&3); the source
  // chunk is pre-permuted: sch = (l&3) ^ ((l>>3)&3)  [= slot ^ ((row>>1)&3)]
  const int schm = (lane & 3) ^ ((lane >> 3) & 3);
  const unsigned short* Ag =
      A + ((size_t)(row0 + wave * 32 + (lane >> 2))) * DIM + schm * 8;
  const int dstA = wave * 2048;                  // 2 gload_lds: 16 rows each
  const int dstB = 16384 + wave * 1024;          // 16 rows per wave

  // fragment readers: row byte base + swizzled chunk offset
  const int swz = (quad ^ ((lcol >> 1) & 3)) * 16;
  int aoff[4], boff[4];
#pragma unroll
  for (int i = 0; i < 4; ++i) aoff[i] = (wm * 64 + i * 16 + lcol) * 64 + swz;
#pragma unroll
  for (int j = 0; j < 4; ++j) boff[j] = 16384 + (wn * 64 + j * 16 + lcol) * 64 + swz;

#define ASGP const __attribute__((address_space(1))) void*
#define LDSP __attribute__((address_space(3))) void*
#define STAGE(ktv, bb) do {                                                        \
    const unsigned short* As_ = Ag + (ktv) * 32;                                   \
    const unsigned short* Bs_ = Bg + (ktv) * 32;                                   \
    __builtin_amdgcn_global_load_lds((ASGP)(uintptr_t)(As_),                       \
        (LDSP)(uintptr_t)(lds + (bb) + dstA), 16, 0, 0);                           \
    __builtin_amdgcn_global_load_lds((ASGP)(uintptr_t)(As_ + 16 * DIM),            \
        (LDSP)(uintptr_t)(lds + (bb) + dstA + 1024), 16, 0, 0);                    \
    __builtin_amdgcn_global_load_lds((ASGP)(uintptr_t)(Bs_),                       \
        (LDSP)(uintptr_t)(lds + (bb) + dstB), 16, 0, 0);                           \
  } while (0)

// SWAPPED operands: A-operand = code fragment (bv), B-operand = row fragment
// (af). Operand input layouts are (lane&15, quad)-symmetric, so the same
// loads feed either slot. acc[i][j]: i = code-block, j = row-block;
// D reg axis (quad*4+r) = code, D lane axis (lcol) = z-row.
#define COMPUTE(cbb) do {                                                          \
    short8 af[4], bv[4];                                                           \
    _Pragma("unroll")                                                              \
    for (int i = 0; i < 4; ++i) af[i] = *(const short8*)(lds + (cbb) + aoff[i]);   \
    _Pragma("unroll")                                                              \
    for (int j = 0; j < 4; ++j) bv[j] = *(const short8*)(lds + (cbb) + boff[j]);   \
    _Pragma("unroll")                                                              \
    for (int i = 0; i < 4; ++i)                                                    \
      _Pragma("unroll")                                                            \
      for (int j = 0; j < 4; ++j)                                                  \
        acc[i][j] = __builtin_amdgcn_mfma_f32_16x16x32_bf16(bv[i], af[j],          \
                                                            acc[i][j], 0, 0, 0);   \
  } while (0)

#pragma unroll 1
  for (int ct = 0; ct < 8; ++ct) {
    const int c0 = cstart + ct * 128;
    const unsigned short* Bg =
        B + ((size_t)(c0 + wave * 16 + (lane >> 2))) * DIM + schm * 8;

    f32x4 acc[4][4];
#pragma unroll
    for (int i = 0; i < 4; ++i)
#pragma unroll
      for (int j = 0; j < 4; ++j) acc[i][j] = 0.f;

    __syncthreads();                 // staging region free (all ds_reads done)
    STAGE(0, 0);
    STAGE(1, 24576);
    int cb = 0, nb = 24576, fb = 49152;   // rotating buffer bases
#pragma unroll 1
    for (int kt = 0; kt < 15; ++kt) {
      // own STAGE(kt) landed (in-order retirement; kt+1 may stay in flight)
      asm volatile("s_waitcnt vmcnt(3)" ::: "memory");
      __builtin_amdgcn_s_barrier();          // => ALL waves' STAGE(kt) landed
      asm volatile("" ::: "memory");         // no memory op hoists above barrier
      __builtin_amdgcn_sched_barrier(0);
      // fb == buffer read at COMPUTE(kt-1); its readers retired their ds_reads
      // before the barrier above -> safe to overwrite now.
      if (kt < 14) STAGE(kt + 2, fb);
      COMPUTE(cb);
      const int t = cb; cb = nb; nb = fb; fb = t;
    }
    asm volatile("s_waitcnt vmcnt(0)" ::: "memory");
    __builtin_amdgcn_s_barrier();
    asm volatile("" ::: "memory");
    __builtin_amdgcn_sched_barrier(0);
    COMPUTE(cb);                     // kt=15 (15%3==0 -> cb cycled back to 0)

    // ---- in-register scan: 64 scores/lane, no LDS round-trip ----
#pragma unroll
    for (int i = 0; i < 4; ++i) {
      const int eb = ct * 128 + wn * 64 + i * 16 + quad * 4;
      const float e0 = e2sAll[eb], e1 = e2sAll[eb + 1];
      const float e2v = e2sAll[eb + 2], e3 = e2sAll[eb + 3];
      const int id0 = cstart + eb;
      SCAN_J(0); SCAN_J(1); SCAN_J(2); SCAN_J(3);
    }
  }

  // butterfly merge across the 4 quad-lanes (snapshot-then-insert; (key,id)
  // lexicographic -> all 4 lanes end with the identical union top-4)
  MERGE_STEP(0, 16); MERGE_STEP(1, 16); MERGE_STEP(2, 16); MERGE_STEP(3, 16);
  MERGE_STEP(0, 32); MERGE_STEP(1, 32); MERGE_STEP(2, 32); MERGE_STEP(3, 32);

  if (quad == 0) {
#define WOUT(J) do { \
      const size_t cb2 = ((size_t)(row0 + wm * 64 + (J) * 16 + lcol)) * 64 + by * 8 + wn * 4; \
      float4 kf; kf.x = tk##J##0; kf.y = tk##J##1; kf.z = tk##J##2; kf.w = tk##J##3; \
      int4 fi; fi.x = ti##J##0; fi.y = ti##J##1; fi.z = ti##J##2; fi.w = ti##J##3; \
      *(float4*)(candk + cb2) = kf; *(int4*)(candi + cb2) = fi; \
    } while (0)
    WOUT(0); WOUT(1); WOUT(2); WOUT(3);
  }
}

// ---------------- 3) np-faithful fp32 rescore, wave-per-row ----------------
// One wave per row; LANE j owns candidate j (64 in parallel). Per-candidate
// arithmetic bit-identical: OpenBLAS sgemm model m32 = RN32(chain(0..383) +
// chain(384..511)), sequential fp32 fma chains; d = RN32(RN32(a+b)-RN32(2m)).
// Winner = lexicographic min (d, c).
__global__ __launch_bounds__(256) void rescore_np(
    const float* __restrict__ z, const float* __restrict__ e,
    const float* __restrict__ a32, const float* __restrict__ b32,
    const float* __restrict__ candk, const int* __restrict__ candi,
    float* __restrict__ idxout)
{
  const int row = blockIdx.x * 4 + (threadIdx.x >> 6);
  const int lane = threadIdx.x & 63;

  const float myk = candk[(size_t)row * 64 + lane];
  float kmin = myk;
#pragma unroll
  for (int m = 1; m < 64; m <<= 1) kmin = fminf(kmin, __shfl_xor(kmin, m, 64));
  const float cut = kmin + MARGIN;

  float bd = 3.4e38f;
  int bc = 0x7fffffff;
  if (myk <= cut) {
    const int c = candi[(size_t)row * 64 + lane];
    const float* zr = z + (size_t)row * DIM;
    const float* er = e + (size_t)c * DIM;
    // panel A: k = 0..383, sequential fp32 fma chain
    float s = 0.0f;
#pragma unroll 4
    for (int k4 = 0; k4 < 96; ++k4) {
      const float4 zv = *(const float4*)(zr + k4 * 4);
      const float4 ev = *(const float4*)(er + k4 * 4);
      s = fmaf(zv.x, ev.x, s);
      s = fmaf(zv.y, ev.y, s);
      s = fmaf(zv.z, ev.z, s);
      s = fmaf(zv.w, ev.w, s);
    }
    const float cA = s;
    // panel B: k = 384..511
    s = 0.0f;
#pragma unroll 4
    for (int k4 = 96; k4 < 128; ++k4) {
      const float4 zv = *(const float4*)(zr + k4 * 4);
      const float4 ev = *(const float4*)(er + k4 * 4);
      s = fmaf(zv.x, ev.x, s);
      s = fmaf(zv.y, ev.y, s);
      s = fmaf(zv.z, ev.z, s);
      s = fmaf(zv.w, ev.w, s);
    }
    const float m = cA + s;                    // RN32 panel combine
    const float t1 = a32[row] + b32[c];        // RN32(a + b_c)
    const float t2 = opaque_f(2.0f * m);       // RN32(2*m), no contraction
    bd = t1 - t2;                              // RN32(t1 - t2)
    bc = c;
  }
  // lexicographic (d, c) min across the wave
#pragma unroll
  for (int mm = 1; mm < 64; mm <<= 1) {
    const float od = __shfl_xor(bd, mm, 64);
    const int oc = __shfl_xor(bc, mm, 64);
    if (od < bd || (od == bd && oc < bc)) { bd = od; bc = oc; }
  }
  if (lane == 0) idxout[row] = (float)bc;
}

// ---------------- 4) gather + straight-through output + loss ---------------
// Grid-stride over 4,194,304 float4-chunks with 1024 blocks: ONE fp64 atomic
// per block.
__global__ __launch_bounds__(256) void writeout_k(
    const float* __restrict__ z, const float* __restrict__ e,
    const float* __restrict__ idxf, float* __restrict__ outq,
    double* __restrict__ accum)
{
  const int tid = threadIdx.x;
  double s = 0.0;
  size_t gid = (size_t)blockIdx.x * 256 + tid;
#pragma unroll 1
  for (int it = 0; it < 16; ++it, gid += 262144) {
    const int row = (int)(gid >> 7);
    const int dq = ((int)gid & 127) << 2;
    const int c = (int)idxf[row];
    const float4 q4 = *(const float4*)(e + (size_t)c * DIM + dq);
    const float4 z4 = *(const float4*)(z + (size_t)row * DIM + dq);
    const float tx = q4.x - z4.x, ty = q4.y - z4.y, tz = q4.z - z4.z, tw = q4.w - z4.w;
    float4 o;
    o.x = z4.x + tx; o.y = z4.y + ty; o.z = z4.z + tz; o.w = z4.w + tw;
    *(float4*)(outq + (size_t)row * DIM + dq) = o;
    s += (double)tx * tx + (double)ty * ty + (double)tz * tz + (double)tw * tw;
  }
#pragma unroll
  for (int m = 1; m < 64; m <<= 1) s += shfl_xor_dbl(s, m);
  __shared__ double wsum[4];
  if ((tid & 63) == 0) wsum[tid >> 6] = s;
  __syncthreads();
  if (tid == 0) atomicAdd(accum, wsum[0] + wsum[1] + wsum[2] + wsum[3]);
}

// ---------------- 5) finalize loss -----------------------------------------
__global__ void finalize_k(const double* __restrict__ accum, float* __restrict__ lossp) {
  *lossp = (float)(1.25 * accum[0] / (double)((size_t)N_ROWS * DIM));
}

// ---------------------------------------------------------------------------
extern "C" void kernel_launch(void* const* d_in, const int* in_sizes, int n_in,
                              void* d_out, int out_size, void* d_ws, size_t ws_size,
                              hipStream_t stream) {
  const float* z = (const float*)d_in[0];   // [32768*512] f32
  const float* e = (const float*)d_in[1];   // [8192*512]  f32
  float* out = (float*)d_out;
  char* ob = (char*)d_out;

  // scratch inside the 64MB quantized region (overwritten by writeout_k)
  unsigned short* zb = (unsigned short*)ob;                  // 33,554,432 B
  unsigned short* eb = (unsigned short*)(ob + 33554432);     //  8,388,608 B
  float* b32   = (float*)(ob + 41943040);                    //     32,768 B
  float* a32   = (float*)(ob + 41975808);                    //    131,072 B
  float* candk = (float*)(ob + 42106880);                    //  8,388,608 B
  int*   candi = (int*)(ob + 50495488);                      //  8,388,608 B

  float* lossp = out + 16777216;
  float* idxs  = out + 16777217;
  double* accum = (double*)d_ws;

  hipMemsetAsync(d_ws, 0, sizeof(double), stream);
  cvtnorm_k<<<8192, 256, 0, stream>>>(z, zb, a32);
  cvtnorm_k<<<2048, 256, 0, stream>>>(e, eb, b32);
  gemm_topk<<<1024, 512, 0, stream>>>(zb, eb, b32, candk, candi);
  rescore_np<<<8192, 256, 0, stream>>>(z, e, a32, b32, candk, candi, idxs);
  writeout_k<<<1024, 256, 0, stream>>>(z, e, idxs, out, accum);
  finalize_k<<<1, 1, 0, stream>>>(accum, lossp);
}